// Round 7
// baseline (748.705 us; speedup 1.0000x reference)
//
#include <hip/hip_runtime.h>
#include <math.h>

// Problem constants
#define NQ   65536
#define H    32
#define IN   64
#define OUTC 64
#define K    15
#define QB   16          // queries per tile
#define S_XN 68          // xn row stride (bf16 elems), proven conflict-free (R4)
#define S_WT 36          // wT row stride (R4)
#define AK   72          // Awt k_kp stride (R4, 0 conflicts measured)
#define AROW 1076        // Awt per-query row stride (R4)
#define INV_EXT (1.0f / 0.048f)
#define GRID 1024        // 4 blocks/CU x 256 CU -- guaranteed co-resident (LDS 35840*4=143KB<160KB)

// d_ws layout (bytes)
#define OFF_PSUM  131072                       // psum [2][1024][64] float = 512 KB
#define OFF_SCSH  655360                       // 128 floats
#define OFF_BAR   656384                       // 2 unsigned (barrier cnt/gen)
#define OFF_XBF   786432                       // x in bf16: 8 MB
#define NEED_BF16 (OFF_XBF + (size_t)NQ * IN * 2)

typedef __attribute__((ext_vector_type(8))) short short8;
typedef __attribute__((ext_vector_type(4))) short short4v;
typedef __attribute__((ext_vector_type(4))) float float4v;

static __device__ __forceinline__ unsigned short f2bf(float f) {
    return (unsigned short)((__float_as_uint(f) + 0x8000u) >> 16);
}
static __device__ __forceinline__ unsigned pk2(float a, float b) {
    return (__float_as_uint(a) + 0x8000u) >> 16 |
           ((__float_as_uint(b) + 0x8000u) & 0xFFFF0000u);
}

// Generation-counting grid barrier: device-scope atomics + fences (XCD-safe).
static __device__ __forceinline__ void grid_barrier(unsigned* cnt, unsigned* gen, int tid) {
    __syncthreads();
    if (tid == 0) {
        __threadfence();   // release all prior writes to device scope
        const unsigned g = __hip_atomic_load(gen, __ATOMIC_ACQUIRE, __HIP_MEMORY_SCOPE_AGENT);
        const unsigned a = __hip_atomic_fetch_add(cnt, 1u, __ATOMIC_ACQ_REL, __HIP_MEMORY_SCOPE_AGENT);
        if (a == GRID - 1) {
            __hip_atomic_store(cnt, 0u, __ATOMIC_RELAXED, __HIP_MEMORY_SCOPE_AGENT);
            __hip_atomic_fetch_add(gen, 1u, __ATOMIC_ACQ_REL, __HIP_MEMORY_SCOPE_AGENT);
        } else {
            while (__hip_atomic_load(gen, __ATOMIC_ACQUIRE, __HIP_MEMORY_SCOPE_AGENT) == g)
                __builtin_amdgcn_s_sleep(8);
        }
        __threadfence();   // acquire: invalidate stale caches before reads
    }
    __syncthreads();
}

// ---------------------------------------------------------------------------
// ONE kernel, manual grid barriers:
//   prep -> BAR -> 4x KPConv tile (R4 body) + psum -> BAR -> BN stats -> BAR
//   -> apply BN+LeakyReLU from registers -> single out write.
// ---------------------------------------------------------------------------
template<bool BFX>
__global__ __launch_bounds__(256, 4) void fused(
    const float* __restrict__ x, unsigned short* __restrict__ xbf,
    const float* __restrict__ qp, const float* __restrict__ sp,
    const int* __restrict__ inds, const float* __restrict__ kp,
    const float* __restrict__ W, const float* __restrict__ gamma,
    const float* __restrict__ beta, short* __restrict__ Bfrag,
    float* __restrict__ psum, float* __restrict__ sc_sh,
    unsigned* __restrict__ bar, float* __restrict__ out)
{
    __shared__ __align__(16) short lds[17920];            // 35840 B, 4 blk/CU
    short* xn  = lds;                                     // [4][32][S_XN] = 8704
    short* wT  = lds + 8704;                              // [16][16][S_WT] = 9216
    short* Awt = lds;                                     // phase 2: 17216

    const int tid  = threadIdx.x;
    const int lane = tid & 63;
    const int wv   = tid >> 6;
    const int quad = lane >> 4;
    const int ml   = lane & 15;
    const int bid  = blockIdx.x;

    // ================= Phase 0: prep =================
    if (BFX) {
#pragma unroll
        for (int i = 0; i < 4; ++i) {
            const int t = bid * 256 + tid + i * 262144;    // float4 index
            const float4 v = ((const float4*)x)[t];
            uint2 p; p.x = pk2(v.x, v.y); p.y = pk2(v.z, v.w);
            ((uint2*)xbf)[t] = p;
        }
    }
    if (bid < 240) {                                       // W repack (R4 mapping)
        const int t2 = bid * 256 + tid;
        const int o  = t2 & 63;
        const int i  = (t2 >> 6) & 63;
        const int kq = t2 >> 12;
        const int t  = kq * 2 + (i >> 5);
        const int ln = ((i >> 3) & 3) * 16 + (o & 15);
        const int v  = o >> 4;
        const int j  = i & 7;
        Bfrag[((v * 30 + t) * 64 + ln) * 8 + j] = (short)f2bf(W[t2]);
    }
    grid_barrier(bar, bar + 1, tid);

    // ================= Phase 1: 4 KPConv tiles (R4 body) =================
    float4v oacc[4];
    float s = 0.f, s2 = 0.f;

    for (int tl = 0; tl < 4; ++tl) {
        const int q0 = (bid * 4 + tl) * QB;
        __syncthreads();          // prev tile's Awt reads done before wT reuse

        // ---- Stage A: influence weights -> wT[q][k][h] bf16 ----
        for (int rep = 0; rep < 2; ++rep) {
            const int pair = tid + rep * 256;
            const int q = pair >> 5, h = pair & 31;
            const int n = q0 + q;
            const int id = inds[n * H + h];
            const float dx = sp[id * 3 + 0] - qp[n * 3 + 0];
            const float dy = sp[id * 3 + 1] - qp[n * 3 + 1];
            const float dz = sp[id * 3 + 2] - qp[n * 3 + 2];
#pragma unroll
            for (int k = 0; k < K; ++k) {
                const float ex = dx - kp[k * 3 + 0];
                const float ey = dy - kp[k * 3 + 1];
                const float ez = dz - kp[k * 3 + 2];
                const float sq = ex * ex + ey * ey + ez * ez;
                float wval = 1.0f - __builtin_amdgcn_sqrtf(sq) * INV_EXT;
                wval = wval > 0.0f ? wval : 0.0f;
                wT[(q * 16 + k) * S_WT + h] = (short)f2bf(wval);
            }
            wT[(q * 16 + K) * S_WT + h] = 0;
        }
        __syncthreads();

        // ---- Stage 1: per query C[k][i] = sum_h w[h][k]*xn[h][i] ----
        float4v frag[QB];
#pragma unroll
        for (int qg = 0; qg < QB; ++qg) frag[qg] = (float4v){0.f, 0.f, 0.f, 0.f};

        for (int b = 0; b < 4; ++b) {
            const int ibase = (q0 + 4 * b + wv) * H;
#pragma unroll
            for (int j = 0; j < 8; ++j) {
                const int h = j * 4 + quad;
                const int id = inds[ibase + h];            // quad-uniform bcast
                if (BFX) {
                    const short4v xv = *(const short4v*)((const short*)xbf + id * IN + ml * 4);
                    *(short4v*)&xn[(wv * H + h) * S_XN + ml * 4] = xv;
                } else {
                    const float4 xv = *(const float4*)(x + id * IN + ml * 4);
                    short4v p;
                    p[0] = (short)f2bf(xv.x); p[1] = (short)f2bf(xv.y);
                    p[2] = (short)f2bf(xv.z); p[3] = (short)f2bf(xv.w);
                    *(short4v*)&xn[(wv * H + h) * S_XN + ml * 4] = p;
                }
            }
            __syncthreads();
#pragma unroll
            for (int ql = 0; ql < 4; ++ql) {
                const int qg = 4 * b + ql;
                const int arow = (qg * 16 + ml) * S_WT + quad * 8;
                const short4v alo = *(const short4v*)&wT[arow];
                const short4v ahi = *(const short4v*)&wT[arow + 4];
                short8 a;
#pragma unroll
                for (int e = 0; e < 4; ++e) { a[e] = alo[e]; a[e + 4] = ahi[e]; }
                short8 bb;
#pragma unroll
                for (int j = 0; j < 8; ++j)
                    bb[j] = xn[(ql * H + quad * 8 + j) * S_XN + wv * 16 + ml];
                frag[qg] = __builtin_amdgcn_mfma_f32_16x16x32_bf16(a, bb, frag[qg], 0, 0, 0);
            }
            __syncthreads();
        }

        // ---- Round trip: C-frags -> Awt (stage-2 A layout) ----
#pragma unroll
        for (int qg = 0; qg < QB; ++qg) {
#pragma unroll
            for (int r = 0; r < 4; ++r) {
                const int kq = quad * 4 + r;
                if (kq < K)
                    Awt[qg * AROW + kq * AK + wv * 16 + ml] = (short)f2bf(frag[qg][r]);
            }
        }
        __syncthreads();

        // ---- Stage 2: 30 K-steps ----
        float4v acc = (float4v){0.f, 0.f, 0.f, 0.f};
        const short* bptr = Bfrag + (wv * 30) * 512 + lane * 8;
#pragma unroll 2
        for (int t = 0; t < 30; ++t) {
            const int abase = ml * AROW + (t >> 1) * AK + (t & 1) * 32 + quad * 8;
            const short4v alo = *(const short4v*)&Awt[abase];
            const short4v ahi = *(const short4v*)&Awt[abase + 4];
            short8 a;
#pragma unroll
            for (int e = 0; e < 4; ++e) { a[e] = alo[e]; a[e + 4] = ahi[e]; }
            const short8 bb = *(const short8*)(bptr + t * 512);
            acc = __builtin_amdgcn_mfma_f32_16x16x32_bf16(a, bb, acc, 0, 0, 0);
        }
        oacc[tl] = acc;
#pragma unroll
        for (int r = 0; r < 4; ++r) { s += acc[r]; s2 += acc[r] * acc[r]; }
    }

    // ---- per-block channel partials (non-atomic) ----
    s  += __shfl_xor(s, 16, 64);  s  += __shfl_xor(s, 32, 64);
    s2 += __shfl_xor(s2, 16, 64); s2 += __shfl_xor(s2, 32, 64);
    const int cc = wv * 16 + ml;
    if (quad == 0) {
        psum[bid * 64 + cc]         = s;
        psum[65536 + bid * 64 + cc] = s2;
    }
    grid_barrier(bar, bar + 1, tid);

    // ================= Phase 2: BN stats (blocks 0..63) =================
    if (bid < 64) {
        const int c = bid;
        float ps = 0.f, pq = 0.f;
#pragma unroll
        for (int i = 0; i < 4; ++i) {
            const int b = tid + 256 * i;
            ps += psum[b * 64 + c];
            pq += psum[65536 + b * 64 + c];
        }
#pragma unroll
        for (int off = 32; off; off >>= 1) {
            ps += __shfl_down(ps, off, 64);
            pq += __shfl_down(pq, off, 64);
        }
        float* red = (float*)lds;
        if (lane == 0) { red[wv] = ps; red[4 + wv] = pq; }
        __syncthreads();
        if (tid == 0) {
            ps = red[0] + red[1] + red[2] + red[3];
            pq = red[4] + red[5] + red[6] + red[7];
            const float mean = ps * (1.0f / (float)NQ);
            const float var  = pq * (1.0f / (float)NQ) - mean * mean;
            const float scale = gamma[c] / sqrtf(var + 1e-5f);
            sc_sh[c]      = scale;
            sc_sh[64 + c] = beta[c] - mean * scale;
        }
    }
    grid_barrier(bar, bar + 1, tid);

    // ================= Phase 3: apply BN + LeakyReLU from registers =========
    const float scale = sc_sh[cc];
    const float shift = sc_sh[64 + cc];
#pragma unroll
    for (int tl = 0; tl < 4; ++tl) {
        const int q0 = (bid * 4 + tl) * QB;
#pragma unroll
        for (int r = 0; r < 4; ++r) {
            float v = oacc[tl][r] * scale + shift;
            v = v >= 0.0f ? v : 0.1f * v;
            out[(q0 + quad * 4 + r) * OUTC + cc] = v;
        }
    }
}

// ---------------------------------------------------------------------------
extern "C" void kernel_launch(void* const* d_in, const int* in_sizes, int n_in,
                              void* d_out, int out_size, void* d_ws, size_t ws_size,
                              hipStream_t stream)
{
    (void)in_sizes; (void)n_in; (void)out_size;
    const float* x     = (const float*)d_in[0];
    const float* qp    = (const float*)d_in[1];
    const float* sp    = (const float*)d_in[2];
    const int*   inds  = (const int*)d_in[3];
    const float* kp    = (const float*)d_in[4];
    const float* W     = (const float*)d_in[5];
    const float* gamma = (const float*)d_in[6];
    const float* beta  = (const float*)d_in[7];
    float* out = (float*)d_out;

    short*          Bfrag = (short*)d_ws;
    float*          psum  = (float*)((char*)d_ws + OFF_PSUM);
    float*          sc_sh = (float*)((char*)d_ws + OFF_SCSH);
    unsigned*       bar   = (unsigned*)((char*)d_ws + OFF_BAR);
    unsigned short* xbf   = (unsigned short*)((char*)d_ws + OFF_XBF);

    const int use_bf = (ws_size >= NEED_BF16) ? 1 : 0;

    // Zero barrier counters (ws is poisoned 0xAA before every timed launch).
    hipMemsetAsync(bar, 0, 8, stream);

    if (use_bf)
        fused<true><<<GRID, 256, 0, stream>>>(x, xbf, qp, sp, inds, kp, W,
                                              gamma, beta, Bfrag, psum, sc_sh, bar, out);
    else
        fused<false><<<GRID, 256, 0, stream>>>(x, xbf, qp, sp, inds, kp, W,
                                               gamma, beta, Bfrag, psum, sc_sh, bar, out);
}

// Round 8
// 182.105 us; speedup vs baseline: 4.1114x; 4.1114x over previous
//
#include <hip/hip_runtime.h>
#include <math.h>

// Problem constants
#define NQ   65536
#define H    32
#define IN   64
#define OUTC 64
#define K    15
#define QB   16          // queries per block
#define S_XN 68          // xn row stride (bf16 elems), conflict-free (R4/R5 measured)
#define S_WT 36          // wT row stride
#define AK   68          // Awt k_kp stride (R5: 0 conflicts measured)
#define AROW 1020        // Awt per-query row stride (R5: 0 conflicts measured)
#define INV_EXT (1.0f / 0.048f)

// d_ws layout (bytes)
#define OFF_PSUM  131072                       // psum [2][64][4096] float = 2 MB
#define OFF_SCSH  (OFF_PSUM + 2097152)         // 128 floats
#define OFF_XBF   (OFF_SCSH + 1024)            // x in bf16: 8 MB
#define NEED_BF16 (OFF_XBF + (size_t)NQ * IN * 2)

typedef __attribute__((ext_vector_type(8))) short short8;
typedef __attribute__((ext_vector_type(4))) short short4v;
typedef __attribute__((ext_vector_type(4))) float float4v;

static __device__ __forceinline__ unsigned short f2bf(float f) {
    return (unsigned short)((__float_as_uint(f) + 0x8000u) >> 16);
}
static __device__ __forceinline__ unsigned pk2(float a, float b) {
    return (__float_as_uint(a) + 0x8000u) >> 16 |
           ((__float_as_uint(b) + 0x8000u) & 0xFFFF0000u);
}

// ---------------------------------------------------------------------------
// Prep: blocks [0,4096): x fp32 -> bf16 (coalesced).
//       blocks [4096,4336): W repack -> stage-2 B-frag dump order.
// ---------------------------------------------------------------------------
__global__ __launch_bounds__(256) void prep_all(
    const float* __restrict__ W, const float* __restrict__ x,
    short* __restrict__ Bfrag, unsigned short* __restrict__ xbf, int do_x)
{
    const int b = blockIdx.x;
    if (b < 4096) {
        if (do_x) {
            const int t = b * 256 + threadIdx.x;      // float4 index
            const float4 v = ((const float4*)x)[t];
            uint2 p; p.x = pk2(v.x, v.y); p.y = pk2(v.z, v.w);
            ((uint2*)xbf)[t] = p;
        }
    } else {
        const int t2 = (b - 4096) * 256 + threadIdx.x;   // flat W index, coalesced
        const int o  = t2 & 63;
        const int i  = (t2 >> 6) & 63;
        const int kq = t2 >> 12;                          // 0..14
        const int t  = kq * 2 + (i >> 5);
        const int lane = ((i >> 3) & 3) * 16 + (o & 15);
        const int v  = o >> 4;
        const int j  = i & 7;
        Bfrag[((v * 30 + t) * 64 + lane) * 8 + j] = (short)f2bf(W[t2]);
    }
}

// ---------------------------------------------------------------------------
// Main: fused KPConv via dual MFMA, R4 body + 32640B LDS (5 blocks/CU).
// Phase1 (per sub-batch): xn[4][32][68]=8704 + wT[4][16][36]=2304;
// Phase2: Awt[16][1020]=16320 (union).
// ---------------------------------------------------------------------------
template<bool BFX>
__global__ __launch_bounds__(256, 4) void kpconv_mfma(
    const float* __restrict__ x, const unsigned short* __restrict__ xbf,
    const float* __restrict__ qp, const float* __restrict__ sp,
    const int* __restrict__ inds, const float* __restrict__ kp,
    const short* __restrict__ Bfrag, float* __restrict__ out_raw,
    float* __restrict__ psum)
{
    __shared__ __align__(16) short lds[16320];            // 32640 B -> 5 blk/CU
    short* xn  = lds;                                     // [4][32][S_XN]
    short* wT  = lds + 8704;                              // [4][16][S_WT]
    short* Awt = lds;                                     // phase 2

    const int tid  = threadIdx.x;
    const int lane = tid & 63;
    const int wv   = tid >> 6;
    const int quad = lane >> 4;
    const int ml   = lane & 15;
    const int q0   = blockIdx.x * QB;

    float4v frag[QB];
#pragma unroll
    for (int qg = 0; qg < QB; ++qg) frag[qg] = (float4v){0.f, 0.f, 0.f, 0.f};

    for (int b = 0; b < 4; ++b) {
        const int nq_ = q0 + 4 * b + wv;      // this wave's staged query

        // ---- Stage A (per-wave): influence weights -> wT[wv][k][h] bf16 ----
        {
            const int h = lane >> 1, half = lane & 1;
            const int idA = inds[nq_ * H + h];
            const float dx = sp[idA * 3 + 0] - qp[nq_ * 3 + 0];
            const float dy = sp[idA * 3 + 1] - qp[nq_ * 3 + 1];
            const float dz = sp[idA * 3 + 2] - qp[nq_ * 3 + 2];
#pragma unroll
            for (int kk = 0; kk < 8; ++kk) {
                const int k = half * 8 + kk;
                float wval = 0.f;
                if (k < K) {
                    const float ex = dx - kp[k * 3 + 0];
                    const float ey = dy - kp[k * 3 + 1];
                    const float ez = dz - kp[k * 3 + 2];
                    const float sq = ex * ex + ey * ey + ez * ez;
                    wval = 1.0f - __builtin_amdgcn_sqrtf(sq) * INV_EXT;
                    wval = wval > 0.0f ? wval : 0.0f;
                }
                wT[(wv * 16 + k) * S_WT + h] = (short)f2bf(wval);
            }
        }

        // ---- gather 32 neighbor rows for this wave's query (R4 form) ----
        const int ibase = nq_ * H;
#pragma unroll
        for (int j = 0; j < 8; ++j) {
            const int h = j * 4 + quad;
            const int id = inds[ibase + h];            // quad-uniform bcast
            if (BFX) {
                const short4v xv = *(const short4v*)((const short*)xbf + id * IN + ml * 4);
                *(short4v*)&xn[(wv * H + h) * S_XN + ml * 4] = xv;
            } else {
                const float4 xv = *(const float4*)(x + id * IN + ml * 4);
                short4v p;
                p[0] = (short)f2bf(xv.x); p[1] = (short)f2bf(xv.y);
                p[2] = (short)f2bf(xv.z); p[3] = (short)f2bf(xv.w);
                *(short4v*)&xn[(wv * H + h) * S_XN + ml * 4] = p;
            }
        }
        __syncthreads();

        // ---- MFMA: 4 queries of this sub-batch, n-tile = wv ----
#pragma unroll
        for (int ql = 0; ql < 4; ++ql) {
            const int qg = 4 * b + ql;
            const int arow = (ql * 16 + ml) * S_WT + quad * 8;
            const short4v alo = *(const short4v*)&wT[arow];
            const short4v ahi = *(const short4v*)&wT[arow + 4];
            short8 a;
#pragma unroll
            for (int e = 0; e < 4; ++e) { a[e] = alo[e]; a[e + 4] = ahi[e]; }
            short8 bb;
#pragma unroll
            for (int j = 0; j < 8; ++j)
                bb[j] = xn[(ql * H + quad * 8 + j) * S_XN + wv * 16 + ml];
            frag[qg] = __builtin_amdgcn_mfma_f32_16x16x32_bf16(a, bb, frag[qg], 0, 0, 0);
        }
        __syncthreads();
    }

    // ---- Round trip: C-frags -> Awt (stage-2 A layout, bf16) ----
#pragma unroll
    for (int qg = 0; qg < QB; ++qg) {
#pragma unroll
        for (int r = 0; r < 4; ++r) {
            const int kq = quad * 4 + r;
            if (kq < K)
                Awt[qg * AROW + kq * AK + wv * 16 + ml] = (short)f2bf(frag[qg][r]);
        }
    }
    __syncthreads();

    // ---- Stage 2: out[q][o] = sum_{k'} Awt[q][k'] * W'[k'][o] ----
    float4v acc = (float4v){0.f, 0.f, 0.f, 0.f};
    const short* bptr = Bfrag + (wv * 30) * 512 + lane * 8;
#pragma unroll 2
    for (int t = 0; t < 30; ++t) {
        const int abase = ml * AROW + (t >> 1) * AK + (t & 1) * 32 + quad * 8;
        const short4v alo = *(const short4v*)&Awt[abase];
        const short4v ahi = *(const short4v*)&Awt[abase + 4];
        short8 a;
#pragma unroll
        for (int e = 0; e < 4; ++e) { a[e] = alo[e]; a[e + 4] = ahi[e]; }
        const short8 bb = *(const short8*)(bptr + t * 512);
        acc = __builtin_amdgcn_mfma_f32_16x16x32_bf16(a, bb, acc, 0, 0, 0);
    }

    // ---- Epilogue: write raw out + per-block channel sums (BN partials) ----
    float s = 0.f, s2 = 0.f;
#pragma unroll
    for (int r = 0; r < 4; ++r) {
        const float v = acc[r];
        out_raw[(q0 + quad * 4 + r) * OUTC + wv * 16 + ml] = v;
        s += v; s2 += v * v;
    }
    s  += __shfl_xor(s, 16, 64);  s  += __shfl_xor(s, 32, 64);
    s2 += __shfl_xor(s2, 16, 64); s2 += __shfl_xor(s2, 32, 64);
    if (quad == 0) {
        const int c = wv * 16 + ml;
        psum[c * 4096 + blockIdx.x]          = s;
        psum[262144 + c * 4096 + blockIdx.x] = s2;
    }
}

// ---------------------------------------------------------------------------
// BN stats: one block per channel, reduce 4096 partials -> scale/shift
// ---------------------------------------------------------------------------
__global__ __launch_bounds__(256) void bn_stats(
    const float* __restrict__ psum, const float* __restrict__ gamma,
    const float* __restrict__ beta, float* __restrict__ sc_sh)
{
    const int c = blockIdx.x;
    const int t = threadIdx.x;
    float s = 0.f, q = 0.f;
#pragma unroll
    for (int i = 0; i < 16; ++i) {
        s += psum[c * 4096 + t + i * 256];
        q += psum[262144 + c * 4096 + t + i * 256];
    }
    __shared__ float rs[4], rq[4];
#pragma unroll
    for (int off = 32; off; off >>= 1) {
        s += __shfl_down(s, off, 64);
        q += __shfl_down(q, off, 64);
    }
    if ((t & 63) == 0) { rs[t >> 6] = s; rq[t >> 6] = q; }
    __syncthreads();
    if (t == 0) {
        s = rs[0] + rs[1] + rs[2] + rs[3];
        q = rq[0] + rq[1] + rq[2] + rq[3];
        const float mean = s * (1.0f / (float)NQ);
        const float var  = q * (1.0f / (float)NQ) - mean * mean;
        const float scale = gamma[c] / sqrtf(var + 1e-5f);
        sc_sh[c]      = scale;
        sc_sh[64 + c] = beta[c] - mean * scale;
    }
}

// ---------------------------------------------------------------------------
// Apply BN + LeakyReLU(0.1) in place (float4)
// ---------------------------------------------------------------------------
__global__ __launch_bounds__(256) void bn_apply(
    float* __restrict__ out, const float* __restrict__ sc_sh)
{
    __shared__ float sc[64];
    __shared__ float sh[64];
    if (threadIdx.x < 64) {
        sc[threadIdx.x] = sc_sh[threadIdx.x];
        sh[threadIdx.x] = sc_sh[64 + threadIdx.x];
    }
    __syncthreads();
    const int idx = blockIdx.x * 256 + threadIdx.x;
#pragma unroll
    for (int it = 0; it < 4; ++it) {
        const int e = idx + it * 262144;
        float4 v = ((const float4*)out)[e];
        const int cg = (e & 15) * 4;
        float4 r;
        r.x = v.x * sc[cg + 0] + sh[cg + 0];
        r.y = v.y * sc[cg + 1] + sh[cg + 1];
        r.z = v.z * sc[cg + 2] + sh[cg + 2];
        r.w = v.w * sc[cg + 3] + sh[cg + 3];
        r.x = r.x >= 0.0f ? r.x : 0.1f * r.x;
        r.y = r.y >= 0.0f ? r.y : 0.1f * r.y;
        r.z = r.z >= 0.0f ? r.z : 0.1f * r.z;
        r.w = r.w >= 0.0f ? r.w : 0.1f * r.w;
        ((float4*)out)[e] = r;
    }
}

// ---------------------------------------------------------------------------
extern "C" void kernel_launch(void* const* d_in, const int* in_sizes, int n_in,
                              void* d_out, int out_size, void* d_ws, size_t ws_size,
                              hipStream_t stream)
{
    (void)in_sizes; (void)n_in; (void)out_size;
    const float* x     = (const float*)d_in[0];
    const float* qp    = (const float*)d_in[1];
    const float* sp    = (const float*)d_in[2];
    const int*   inds  = (const int*)d_in[3];
    const float* kp    = (const float*)d_in[4];
    const float* W     = (const float*)d_in[5];
    const float* gamma = (const float*)d_in[6];
    const float* beta  = (const float*)d_in[7];
    float* out = (float*)d_out;

    short*          Bfrag = (short*)d_ws;
    float*          psum  = (float*)((char*)d_ws + OFF_PSUM);
    float*          sc_sh = (float*)((char*)d_ws + OFF_SCSH);
    unsigned short* xbf   = (unsigned short*)((char*)d_ws + OFF_XBF);

    const int use_bf = (ws_size >= NEED_BF16) ? 1 : 0;

    prep_all<<<4336, 256, 0, stream>>>(W, x, Bfrag, xbf, use_bf);
    if (use_bf)
        kpconv_mfma<true><<<NQ / QB, 256, 0, stream>>>(x, xbf, qp, sp, inds, kp, Bfrag, out, psum);
    else
        kpconv_mfma<false><<<NQ / QB, 256, 0, stream>>>(x, xbf, qp, sp, inds, kp, Bfrag, out, psum);
    bn_stats<<<64, 256, 0, stream>>>(psum, gamma, beta, sc_sh);
    bn_apply<<<1024, 256, 0, stream>>>(out, sc_sh);
}

// Round 9
// 155.607 us; speedup vs baseline: 4.8115x; 1.1703x over previous
//
#include <hip/hip_runtime.h>
#include <math.h>

// Problem constants
#define NQ   65536
#define H    32
#define IN   64
#define OUTC 64
#define K    15
#define QB   16          // queries per block
#define S_XN 68          // xn row stride (bf16 elems), conflict-free (measured R4)
#define S_WT 36          // wT row stride (R4)
#define AK   72          // Awt k_kp stride (R4, 0 conflicts measured)
#define AROW 1076        // Awt per-query row stride (R4, 0 conflicts measured)
#define INV_EXT (1.0f / 0.048f)

// d_ws layout (bytes)
#define OFF_PSUM  131072                       // psum [2][64][4096] float = 2 MB
#define OFF_SCSH  (OFF_PSUM + 2097152)         // 128 floats
#define OFF_XBF   (OFF_SCSH + 1024)            // x in bf16: 8 MB
#define NEED_BF16 (OFF_XBF + (size_t)NQ * IN * 2)

typedef __attribute__((ext_vector_type(8))) short short8;
typedef __attribute__((ext_vector_type(4))) short short4v;
typedef __attribute__((ext_vector_type(4))) float float4v;

static __device__ __forceinline__ unsigned short f2bf(float f) {
    return (unsigned short)((__float_as_uint(f) + 0x8000u) >> 16);
}
static __device__ __forceinline__ unsigned pk2(float a, float b) {
    return (__float_as_uint(a) + 0x8000u) >> 16 |
           ((__float_as_uint(b) + 0x8000u) & 0xFFFF0000u);
}

// ---------------------------------------------------------------------------
// Prep: blocks [0,4096): x fp32 -> bf16 (coalesced).
//       blocks [4096,4336): W repack -> stage-2 B-frag dump order.
// ---------------------------------------------------------------------------
__global__ __launch_bounds__(256) void prep_all(
    const float* __restrict__ W, const float* __restrict__ x,
    short* __restrict__ Bfrag, unsigned short* __restrict__ xbf, int do_x)
{
    const int b = blockIdx.x;
    if (b < 4096) {
        if (do_x) {
            const int t = b * 256 + threadIdx.x;      // float4 index
            const float4 v = ((const float4*)x)[t];
            uint2 p; p.x = pk2(v.x, v.y); p.y = pk2(v.z, v.w);
            ((uint2*)xbf)[t] = p;
        }
    } else {
        const int t2 = (b - 4096) * 256 + threadIdx.x;   // flat W index, coalesced
        const int o  = t2 & 63;
        const int i  = (t2 >> 6) & 63;
        const int kq = t2 >> 12;                          // 0..14
        const int t  = kq * 2 + (i >> 5);
        const int lane = ((i >> 3) & 3) * 16 + (o & 15);
        const int v  = o >> 4;
        const int j  = i & 7;
        Bfrag[((v * 30 + t) * 64 + lane) * 8 + j] = (short)f2bf(W[t2]);
    }
}

// ---------------------------------------------------------------------------
// Main: R4 body (82us proven) + register-prefetch pipeline on the gather.
// LDS: phase1 xn[4][32][68]=8704 + wT[16][16][36]=9216; phase2 Awt (union).
// ---------------------------------------------------------------------------
template<bool BFX>
__global__ __launch_bounds__(256, 4) void kpconv_mfma(
    const float* __restrict__ x, const unsigned short* __restrict__ xbf,
    const float* __restrict__ qp, const float* __restrict__ sp,
    const int* __restrict__ inds, const float* __restrict__ kp,
    const short* __restrict__ Bfrag, float* __restrict__ out_raw,
    float* __restrict__ psum)
{
    __shared__ __align__(16) short lds[17920];            // 35840 B, 4 blk/CU
    short* xn  = lds;                                     // [4][32][S_XN]
    short* wT  = lds + 8704;                              // [16][16][S_WT]
    short* Awt = lds;                                     // phase 2

    const int tid  = threadIdx.x;
    const int lane = tid & 63;
    const int wv   = tid >> 6;
    const int quad = lane >> 4;
    const int ml   = lane & 15;
    const int q0   = blockIdx.x * QB;

    // ---- Prefetch sub-batch 0 gather (flies under stage A) ----
    short4v xv[8];
    float4  xf[8];
    {
        const int ibase = (q0 + wv) * H;
#pragma unroll
        for (int j = 0; j < 8; ++j) {
            const int id = inds[ibase + j * 4 + quad];
            if (BFX) xv[j] = *(const short4v*)((const short*)xbf + id * IN + ml * 4);
            else     xf[j] = *(const float4*)(x + id * IN + ml * 4);
        }
    }

    // ---- Stage A (R4 exact): influence weights -> wT[q][k][h] bf16 ----
    for (int rep = 0; rep < 2; ++rep) {
        const int pair = tid + rep * 256;
        const int q = pair >> 5, h = pair & 31;
        const int n = q0 + q;
        const int id = inds[n * H + h];
        const float dx = sp[id * 3 + 0] - qp[n * 3 + 0];
        const float dy = sp[id * 3 + 1] - qp[n * 3 + 1];
        const float dz = sp[id * 3 + 2] - qp[n * 3 + 2];
#pragma unroll
        for (int k = 0; k < K; ++k) {
            const float ex = dx - kp[k * 3 + 0];
            const float ey = dy - kp[k * 3 + 1];
            const float ez = dz - kp[k * 3 + 2];
            const float sq = ex * ex + ey * ey + ez * ez;
            float wval = 1.0f - __builtin_amdgcn_sqrtf(sq) * INV_EXT;
            wval = wval > 0.0f ? wval : 0.0f;
            wT[(q * 16 + k) * S_WT + h] = (short)f2bf(wval);
        }
        wT[(q * 16 + K) * S_WT + h] = 0;
    }

    // ---- Stage 1 with pipelined gather ----
    float4v frag[QB];
#pragma unroll
    for (int qg = 0; qg < QB; ++qg) frag[qg] = (float4v){0.f, 0.f, 0.f, 0.f};

    for (int b = 0; b < 4; ++b) {
        // write prefetched rows to xn (vmcnt wait lands here)
#pragma unroll
        for (int j = 0; j < 8; ++j) {
            const int h = j * 4 + quad;
            if (BFX) {
                *(short4v*)&xn[(wv * H + h) * S_XN + ml * 4] = xv[j];
            } else {
                short4v p;
                p[0] = (short)f2bf(xf[j].x); p[1] = (short)f2bf(xf[j].y);
                p[2] = (short)f2bf(xf[j].z); p[3] = (short)f2bf(xf[j].w);
                *(short4v*)&xn[(wv * H + h) * S_XN + ml * 4] = p;
            }
        }
        __syncthreads();   // b==0: also covers stage-A wT writes

        // issue next sub-batch's gather: flies under MFMA + barrier + epilogue
        if (b < 3) {
            const int ibase = (q0 + 4 * (b + 1) + wv) * H;
#pragma unroll
            for (int j = 0; j < 8; ++j) {
                const int id = inds[ibase + j * 4 + quad];
                if (BFX) xv[j] = *(const short4v*)((const short*)xbf + id * IN + ml * 4);
                else     xf[j] = *(const float4*)(x + id * IN + ml * 4);
            }
        }

        // MFMA: 4 queries of this sub-batch, n-tile = wv
#pragma unroll
        for (int ql = 0; ql < 4; ++ql) {
            const int qg = 4 * b + ql;
            const int arow = (qg * 16 + ml) * S_WT + quad * 8;
            const short4v alo = *(const short4v*)&wT[arow];
            const short4v ahi = *(const short4v*)&wT[arow + 4];
            short8 a;
#pragma unroll
            for (int e = 0; e < 4; ++e) { a[e] = alo[e]; a[e + 4] = ahi[e]; }
            short8 bb;
#pragma unroll
            for (int j = 0; j < 8; ++j)
                bb[j] = xn[(ql * H + quad * 8 + j) * S_XN + wv * 16 + ml];
            frag[qg] = __builtin_amdgcn_mfma_f32_16x16x32_bf16(a, bb, frag[qg], 0, 0, 0);
        }
        __syncthreads();
    }

    // ---- Round trip: C-frags -> Awt (stage-2 A layout, bf16) ----
#pragma unroll
    for (int qg = 0; qg < QB; ++qg) {
#pragma unroll
        for (int r = 0; r < 4; ++r) {
            const int kq = quad * 4 + r;
            if (kq < K)
                Awt[qg * AROW + kq * AK + wv * 16 + ml] = (short)f2bf(frag[qg][r]);
        }
    }
    __syncthreads();

    // ---- Stage 2: out[q][o] = sum_{k'} Awt[q][k'] * W'[k'][o] ----
    float4v acc = (float4v){0.f, 0.f, 0.f, 0.f};
    const short* bptr = Bfrag + (wv * 30) * 512 + lane * 8;
#pragma unroll 2
    for (int t = 0; t < 30; ++t) {
        const int abase = ml * AROW + (t >> 1) * AK + (t & 1) * 32 + quad * 8;
        const short4v alo = *(const short4v*)&Awt[abase];
        const short4v ahi = *(const short4v*)&Awt[abase + 4];
        short8 a;
#pragma unroll
        for (int e = 0; e < 4; ++e) { a[e] = alo[e]; a[e + 4] = ahi[e]; }
        const short8 bb = *(const short8*)(bptr + t * 512);
        acc = __builtin_amdgcn_mfma_f32_16x16x32_bf16(a, bb, acc, 0, 0, 0);
    }

    // ---- Epilogue: write raw out + per-block channel sums (BN partials) ----
    float s = 0.f, s2 = 0.f;
#pragma unroll
    for (int r = 0; r < 4; ++r) {
        const float v = acc[r];
        out_raw[(q0 + quad * 4 + r) * OUTC + wv * 16 + ml] = v;
        s += v; s2 += v * v;
    }
    s  += __shfl_xor(s, 16, 64);  s  += __shfl_xor(s, 32, 64);
    s2 += __shfl_xor(s2, 16, 64); s2 += __shfl_xor(s2, 32, 64);
    if (quad == 0) {
        const int c = wv * 16 + ml;
        psum[c * 4096 + blockIdx.x]          = s;
        psum[262144 + c * 4096 + blockIdx.x] = s2;
    }
}

// ---------------------------------------------------------------------------
// BN stats: one block per channel, reduce 4096 partials -> scale/shift
// ---------------------------------------------------------------------------
__global__ __launch_bounds__(256) void bn_stats(
    const float* __restrict__ psum, const float* __restrict__ gamma,
    const float* __restrict__ beta, float* __restrict__ sc_sh)
{
    const int c = blockIdx.x;
    const int t = threadIdx.x;
    float s = 0.f, q = 0.f;
#pragma unroll
    for (int i = 0; i < 16; ++i) {
        s += psum[c * 4096 + t + i * 256];
        q += psum[262144 + c * 4096 + t + i * 256];
    }
    __shared__ float rs[4], rq[4];
#pragma unroll
    for (int off = 32; off; off >>= 1) {
        s += __shfl_down(s, off, 64);
        q += __shfl_down(q, off, 64);
    }
    if ((t & 63) == 0) { rs[t >> 6] = s; rq[t >> 6] = q; }
    __syncthreads();
    if (t == 0) {
        s = rs[0] + rs[1] + rs[2] + rs[3];
        q = rq[0] + rq[1] + rq[2] + rq[3];
        const float mean = s * (1.0f / (float)NQ);
        const float var  = q * (1.0f / (float)NQ) - mean * mean;
        const float scale = gamma[c] / sqrtf(var + 1e-5f);
        sc_sh[c]      = scale;
        sc_sh[64 + c] = beta[c] - mean * scale;
    }
}

// ---------------------------------------------------------------------------
// Apply BN + LeakyReLU(0.1) in place (float4)
// ---------------------------------------------------------------------------
__global__ __launch_bounds__(256) void bn_apply(
    float* __restrict__ out, const float* __restrict__ sc_sh)
{
    __shared__ float sc[64];
    __shared__ float sh[64];
    if (threadIdx.x < 64) {
        sc[threadIdx.x] = sc_sh[threadIdx.x];
        sh[threadIdx.x] = sc_sh[64 + threadIdx.x];
    }
    __syncthreads();
    const int idx = blockIdx.x * 256 + threadIdx.x;
#pragma unroll
    for (int it = 0; it < 4; ++it) {
        const int e = idx + it * 262144;
        float4 v = ((const float4*)out)[e];
        const int cg = (e & 15) * 4;
        float4 r;
        r.x = v.x * sc[cg + 0] + sh[cg + 0];
        r.y = v.y * sc[cg + 1] + sh[cg + 1];
        r.z = v.z * sc[cg + 2] + sh[cg + 2];
        r.w = v.w * sc[cg + 3] + sh[cg + 3];
        r.x = r.x >= 0.0f ? r.x : 0.1f * r.x;
        r.y = r.y >= 0.0f ? r.y : 0.1f * r.y;
        r.z = r.z >= 0.0f ? r.z : 0.1f * r.z;
        r.w = r.w >= 0.0f ? r.w : 0.1f * r.w;
        ((float4*)out)[e] = r;
    }
}

// ---------------------------------------------------------------------------
extern "C" void kernel_launch(void* const* d_in, const int* in_sizes, int n_in,
                              void* d_out, int out_size, void* d_ws, size_t ws_size,
                              hipStream_t stream)
{
    (void)in_sizes; (void)n_in; (void)out_size;
    const float* x     = (const float*)d_in[0];
    const float* qp    = (const float*)d_in[1];
    const float* sp    = (const float*)d_in[2];
    const int*   inds  = (const int*)d_in[3];
    const float* kp    = (const float*)d_in[4];
    const float* W     = (const float*)d_in[5];
    const float* gamma = (const float*)d_in[6];
    const float* beta  = (const float*)d_in[7];
    float* out = (float*)d_out;

    short*          Bfrag = (short*)d_ws;
    float*          psum  = (float*)((char*)d_ws + OFF_PSUM);
    float*          sc_sh = (float*)((char*)d_ws + OFF_SCSH);
    unsigned short* xbf   = (unsigned short*)((char*)d_ws + OFF_XBF);

    const int use_bf = (ws_size >= NEED_BF16) ? 1 : 0;

    prep_all<<<4336, 256, 0, stream>>>(W, x, Bfrag, xbf, use_bf);
    if (use_bf)
        kpconv_mfma<true><<<NQ / QB, 256, 0, stream>>>(x, xbf, qp, sp, inds, kp, Bfrag, out, psum);
    else
        kpconv_mfma<false><<<NQ / QB, 256, 0, stream>>>(x, xbf, qp, sp, inds, kp, Bfrag, out, psum);
    bn_stats<<<64, 256, 0, stream>>>(psum, gamma, beta, sc_sh);
    bn_apply<<<1024, 256, 0, stream>>>(out, sc_sh);
}

// Round 10
// 152.701 us; speedup vs baseline: 4.9031x; 1.0190x over previous
//
#include <hip/hip_runtime.h>
#include <math.h>

// Problem constants
#define NQ   65536
#define H    32
#define IN   64
#define OUTC 64
#define K    15
#define QB   16          // queries per block
#define S_XN 68          // xn row stride (bf16 elems), conflict-free (measured R4/R9)
#define S_WT 36          // wT row stride
#define AK   72          // Awt k_kp stride (R4/R9, 0 conflicts measured)
#define AROW 1076        // Awt per-query row stride (R4/R9, 0 conflicts measured)
#define INV_EXT (1.0f / 0.048f)

// d_ws layout (bytes)
#define OFF_PSUM  131072                       // psum [2][64][4096] float = 2 MB
#define OFF_SCSH  (OFF_PSUM + 2097152)         // 128 floats
#define OFF_XBF   (OFF_SCSH + 1024)            // x in bf16: 8 MB
#define NEED_BF16 (OFF_XBF + (size_t)NQ * IN * 2)

typedef __attribute__((ext_vector_type(8))) short short8;
typedef __attribute__((ext_vector_type(4))) short short4v;
typedef __attribute__((ext_vector_type(4))) float float4v;

static __device__ __forceinline__ unsigned short f2bf(float f) {
    return (unsigned short)((__float_as_uint(f) + 0x8000u) >> 16);
}
static __device__ __forceinline__ unsigned pk2(float a, float b) {
    return (__float_as_uint(a) + 0x8000u) >> 16 |
           ((__float_as_uint(b) + 0x8000u) & 0xFFFF0000u);
}

// ---------------------------------------------------------------------------
// Prep: blocks [0,4096): x fp32 -> bf16 (coalesced).
//       blocks [4096,4336): W repack -> stage-2 B-frag dump order.
// ---------------------------------------------------------------------------
__global__ __launch_bounds__(256) void prep_all(
    const float* __restrict__ W, const float* __restrict__ x,
    short* __restrict__ Bfrag, unsigned short* __restrict__ xbf, int do_x)
{
    const int b = blockIdx.x;
    if (b < 4096) {
        if (do_x) {
            const int t = b * 256 + threadIdx.x;      // float4 index
            const float4 v = ((const float4*)x)[t];
            uint2 p; p.x = pk2(v.x, v.y); p.y = pk2(v.z, v.w);
            ((uint2*)xbf)[t] = p;
        }
    } else {
        const int t2 = (b - 4096) * 256 + threadIdx.x;   // flat W index, coalesced
        const int o  = t2 & 63;
        const int i  = (t2 >> 6) & 63;
        const int kq = t2 >> 12;                          // 0..14
        const int t  = kq * 2 + (i >> 5);
        const int lane = ((i >> 3) & 3) * 16 + (o & 15);
        const int v  = o >> 4;
        const int j  = i & 7;
        Bfrag[((v * 30 + t) * 64 + lane) * 8 + j] = (short)f2bf(W[t2]);
    }
}

// ---------------------------------------------------------------------------
// Main: barrier-free stage 1. Each wave owns 4 queries (qg = wv*4+qi) and
// computes ALL 4 n-tiles for them -> xn/wT are wave-private (DS ops in-order
// per wave => no __syncthreads in the loop). Only the Awt round-trip (cross-
// wave) keeps 2 barriers. LDS: phase1 xn[4 waves][32][68]=17408B +
// wT[16][16][36]=18432B = 35840B; phase2 Awt[16][1076]=34432B (union).
// ---------------------------------------------------------------------------
template<bool BFX>
__global__ __launch_bounds__(256, 4) void kpconv_mfma(
    const float* __restrict__ x, const unsigned short* __restrict__ xbf,
    const float* __restrict__ qp, const float* __restrict__ sp,
    const int* __restrict__ inds, const float* __restrict__ kp,
    const short* __restrict__ Bfrag, float* __restrict__ out_raw,
    float* __restrict__ psum)
{
    __shared__ __align__(16) short lds[17920];            // 35840 B, 4 blk/CU
    short* xn  = lds;                                     // [4 waves][32][S_XN]
    short* wT  = lds + 8704;                              // [16][16][S_WT]
    short* Awt = lds;                                     // phase 2

    const int tid  = threadIdx.x;
    const int lane = tid & 63;
    const int wv   = tid >> 6;
    const int quad = lane >> 4;
    const int ml   = lane & 15;
    const int q0   = blockIdx.x * QB;

    short* xn_own = xn + wv * (H * S_XN);   // wave-private stage-1 buffer

    // ---- Prefetch query qi=0's gather (flies under stage A) ----
    short4v xv[8];
    float4  xf[8];
    {
        const int ibase = (q0 + wv * 4) * H;
#pragma unroll
        for (int j = 0; j < 8; ++j) {
            const int id = inds[ibase + j * 4 + quad];
            if (BFX) xv[j] = *(const short4v*)((const short*)xbf + id * IN + ml * 4);
            else     xf[j] = *(const float4*)(x + id * IN + ml * 4);
        }
    }

    // ---- Stage A (wave-private): wT for this wave's 4 queries ----
    for (int rep = 0; rep < 2; ++rep) {
        const int p = lane + rep * 64;       // 0..127
        const int qi = p >> 5, h = p & 31;
        const int qg = wv * 4 + qi;
        const int n = q0 + qg;
        const int id = inds[n * H + h];
        const float dx = sp[id * 3 + 0] - qp[n * 3 + 0];
        const float dy = sp[id * 3 + 1] - qp[n * 3 + 1];
        const float dz = sp[id * 3 + 2] - qp[n * 3 + 2];
#pragma unroll
        for (int k = 0; k < K; ++k) {
            const float ex = dx - kp[k * 3 + 0];
            const float ey = dy - kp[k * 3 + 1];
            const float ez = dz - kp[k * 3 + 2];
            const float sq = ex * ex + ey * ey + ez * ez;
            float wval = 1.0f - __builtin_amdgcn_sqrtf(sq) * INV_EXT;
            wval = wval > 0.0f ? wval : 0.0f;
            wT[(qg * 16 + k) * S_WT + h] = (short)f2bf(wval);
        }
        wT[(qg * 16 + K) * S_WT + h] = 0;
    }
    // no barrier: wT rows for qg in [4wv,4wv+4) are read only by this wave

    // ---- Stage 1: barrier-free per-wave loop over own 4 queries ----
    float4v frag[4][4];                      // [qi][n-tile v]
#pragma unroll
    for (int qi = 0; qi < 4; ++qi)
#pragma unroll
        for (int v = 0; v < 4; ++v) frag[qi][v] = (float4v){0.f, 0.f, 0.f, 0.f};

    for (int qi = 0; qi < 4; ++qi) {
        const int qg = wv * 4 + qi;

        // write prefetched rows to wave-private xn (vmcnt wait lands here)
#pragma unroll
        for (int j = 0; j < 8; ++j) {
            const int h = j * 4 + quad;
            if (BFX) {
                *(short4v*)&xn_own[h * S_XN + ml * 4] = xv[j];
            } else {
                short4v p;
                p[0] = (short)f2bf(xf[j].x); p[1] = (short)f2bf(xf[j].y);
                p[2] = (short)f2bf(xf[j].z); p[3] = (short)f2bf(xf[j].w);
                *(short4v*)&xn_own[h * S_XN + ml * 4] = p;
            }
        }

        // issue next query's gather: flies under this query's MFMAs
        if (qi < 3) {
            const int ibase = (q0 + qg + 1) * H;
#pragma unroll
            for (int j = 0; j < 8; ++j) {
                const int id = inds[ibase + j * 4 + quad];
                if (BFX) xv[j] = *(const short4v*)((const short*)xbf + id * IN + ml * 4);
                else     xf[j] = *(const float4*)(x + id * IN + ml * 4);
            }
        }

        // A-frag: per query, shared across the 4 n-tiles (hoisted)
        const int arow = (qg * 16 + ml) * S_WT + quad * 8;
        const short4v alo = *(const short4v*)&wT[arow];
        const short4v ahi = *(const short4v*)&wT[arow + 4];
        short8 a;
#pragma unroll
        for (int e = 0; e < 4; ++e) { a[e] = alo[e]; a[e + 4] = ahi[e]; }

        // 4 MFMAs: n-tiles 0..3 of this query (wave-private LDS reads)
#pragma unroll
        for (int v = 0; v < 4; ++v) {
            short8 bb;
#pragma unroll
            for (int j = 0; j < 8; ++j)
                bb[j] = xn_own[(quad * 8 + j) * S_XN + v * 16 + ml];
            frag[qi][v] = __builtin_amdgcn_mfma_f32_16x16x32_bf16(a, bb, frag[qi][v], 0, 0, 0);
        }
    }

    __syncthreads();   // all waves done with xn/wT before Awt overwrites

    // ---- Round trip: C-frags -> Awt (stage-2 A layout, bf16) ----
#pragma unroll
    for (int qi = 0; qi < 4; ++qi) {
        const int qg = wv * 4 + qi;
#pragma unroll
        for (int v = 0; v < 4; ++v) {
#pragma unroll
            for (int r = 0; r < 4; ++r) {
                const int kq = quad * 4 + r;
                if (kq < K)
                    Awt[qg * AROW + kq * AK + v * 16 + ml] = (short)f2bf(frag[qi][v][r]);
            }
        }
    }
    __syncthreads();

    // ---- Stage 2: out[q][o] = sum_{k'} Awt[q][k'] * W'[k'][o] ----
    float4v acc = (float4v){0.f, 0.f, 0.f, 0.f};
    const short* bptr = Bfrag + (wv * 30) * 512 + lane * 8;
#pragma unroll 2
    for (int t = 0; t < 30; ++t) {
        const int abase = ml * AROW + (t >> 1) * AK + (t & 1) * 32 + quad * 8;
        const short4v alo = *(const short4v*)&Awt[abase];
        const short4v ahi = *(const short4v*)&Awt[abase + 4];
        short8 a;
#pragma unroll
        for (int e = 0; e < 4; ++e) { a[e] = alo[e]; a[e + 4] = ahi[e]; }
        const short8 bb = *(const short8*)(bptr + t * 512);
        acc = __builtin_amdgcn_mfma_f32_16x16x32_bf16(a, bb, acc, 0, 0, 0);
    }

    // ---- Epilogue: write raw out + per-block channel sums (BN partials) ----
    float s = 0.f, s2 = 0.f;
#pragma unroll
    for (int r = 0; r < 4; ++r) {
        const float v = acc[r];
        out_raw[(q0 + quad * 4 + r) * OUTC + wv * 16 + ml] = v;
        s += v; s2 += v * v;
    }
    s  += __shfl_xor(s, 16, 64);  s  += __shfl_xor(s, 32, 64);
    s2 += __shfl_xor(s2, 16, 64); s2 += __shfl_xor(s2, 32, 64);
    if (quad == 0) {
        const int c = wv * 16 + ml;
        psum[c * 4096 + blockIdx.x]          = s;
        psum[262144 + c * 4096 + blockIdx.x] = s2;
    }
}

// ---------------------------------------------------------------------------
// BN stats: one block per channel, reduce 4096 partials -> scale/shift
// ---------------------------------------------------------------------------
__global__ __launch_bounds__(256) void bn_stats(
    const float* __restrict__ psum, const float* __restrict__ gamma,
    const float* __restrict__ beta, float* __restrict__ sc_sh)
{
    const int c = blockIdx.x;
    const int t = threadIdx.x;
    float s = 0.f, q = 0.f;
#pragma unroll
    for (int i = 0; i < 16; ++i) {
        s += psum[c * 4096 + t + i * 256];
        q += psum[262144 + c * 4096 + t + i * 256];
    }
    __shared__ float rs[4], rq[4];
#pragma unroll
    for (int off = 32; off; off >>= 1) {
        s += __shfl_down(s, off, 64);
        q += __shfl_down(q, off, 64);
    }
    if ((t & 63) == 0) { rs[t >> 6] = s; rq[t >> 6] = q; }
    __syncthreads();
    if (t == 0) {
        s = rs[0] + rs[1] + rs[2] + rs[3];
        q = rq[0] + rq[1] + rq[2] + rq[3];
        const float mean = s * (1.0f / (float)NQ);
        const float var  = q * (1.0f / (float)NQ) - mean * mean;
        const float scale = gamma[c] / sqrtf(var + 1e-5f);
        sc_sh[c]      = scale;
        sc_sh[64 + c] = beta[c] - mean * scale;
    }
}

// ---------------------------------------------------------------------------
// Apply BN + LeakyReLU(0.1) in place (float4)
// ---------------------------------------------------------------------------
__global__ __launch_bounds__(256) void bn_apply(
    float* __restrict__ out, const float* __restrict__ sc_sh)
{
    __shared__ float sc[64];
    __shared__ float sh[64];
    if (threadIdx.x < 64) {
        sc[threadIdx.x] = sc_sh[threadIdx.x];
        sh[threadIdx.x] = sc_sh[64 + threadIdx.x];
    }
    __syncthreads();
    const int idx = blockIdx.x * 256 + threadIdx.x;
#pragma unroll
    for (int it = 0; it < 4; ++it) {
        const int e = idx + it * 262144;
        float4 v = ((const float4*)out)[e];
        const int cg = (e & 15) * 4;
        float4 r;
        r.x = v.x * sc[cg + 0] + sh[cg + 0];
        r.y = v.y * sc[cg + 1] + sh[cg + 1];
        r.z = v.z * sc[cg + 2] + sh[cg + 2];
        r.w = v.w * sc[cg + 3] + sh[cg + 3];
        r.x = r.x >= 0.0f ? r.x : 0.1f * r.x;
        r.y = r.y >= 0.0f ? r.y : 0.1f * r.y;
        r.z = r.z >= 0.0f ? r.z : 0.1f * r.z;
        r.w = r.w >= 0.0f ? r.w : 0.1f * r.w;
        ((float4*)out)[e] = r;
    }
}

// ---------------------------------------------------------------------------
extern "C" void kernel_launch(void* const* d_in, const int* in_sizes, int n_in,
                              void* d_out, int out_size, void* d_ws, size_t ws_size,
                              hipStream_t stream)
{
    (void)in_sizes; (void)n_in; (void)out_size;
    const float* x     = (const float*)d_in[0];
    const float* qp    = (const float*)d_in[1];
    const float* sp    = (const float*)d_in[2];
    const int*   inds  = (const int*)d_in[3];
    const float* kp    = (const float*)d_in[4];
    const float* W     = (const float*)d_in[5];
    const float* gamma = (const float*)d_in[6];
    const float* beta  = (const float*)d_in[7];
    float* out = (float*)d_out;

    short*          Bfrag = (short*)d_ws;
    float*          psum  = (float*)((char*)d_ws + OFF_PSUM);
    float*          sc_sh = (float*)((char*)d_ws + OFF_SCSH);
    unsigned short* xbf   = (unsigned short*)((char*)d_ws + OFF_XBF);

    const int use_bf = (ws_size >= NEED_BF16) ? 1 : 0;

    prep_all<<<4336, 256, 0, stream>>>(W, x, Bfrag, xbf, use_bf);
    if (use_bf)
        kpconv_mfma<true><<<NQ / QB, 256, 0, stream>>>(x, xbf, qp, sp, inds, kp, Bfrag, out, psum);
    else
        kpconv_mfma<false><<<NQ / QB, 256, 0, stream>>>(x, xbf, qp, sp, inds, kp, Bfrag, out, psum);
    bn_stats<<<64, 256, 0, stream>>>(psum, gamma, beta, sc_sh);
    bn_apply<<<1024, 256, 0, stream>>>(out, sc_sh);
}